// Round 6
// baseline (475.338 us; speedup 1.0000x reference)
//
#include <hip/hip_runtime.h>

#define NN 8192
#define DD 256
#define FF 128
#define BB 4096
#define NSPLIT 16
#define KCHUNK (NN / NSPLIT)   // 512 keys per split-K chunk
#define NITER (KCHUNK / 64)    // 8 key-tiles per chunk

typedef unsigned short ushortT;
typedef _Float16 f16;
typedef __attribute__((ext_vector_type(8))) _Float16 f16x8;
typedef __attribute__((ext_vector_type(4))) float f32x4;

__device__ __forceinline__ ushortT f2h_bits(float f) {
  f16 h = (f16)f; ushortT u; __builtin_memcpy(&u, &h, 2); return u;
}
__device__ __forceinline__ float h_bits2f(ushortT u) {
  f16 h; __builtin_memcpy(&h, &u, 2); return (float)h;
}

// ---------------- unique(x) compaction ----------------

__global__ __launch_bounds__(256) void init_kernel(int* flags, int* cnt) {
  int i = blockIdx.x * 256 + threadIdx.x;
  flags[i] = 0;
  if (i == 0) *cnt = 0;
}

__global__ __launch_bounds__(256) void scatter_kernel(const int* __restrict__ x, int* flags) {
  int b = blockIdx.x * 256 + threadIdx.x;
  flags[x[b]] = 1;
}

__global__ __launch_bounds__(256) void compact_kernel(const int* __restrict__ flags, int* cnt,
                                                      int* list, int* slot) {
  int i = blockIdx.x * 256 + threadIdx.x;
  if (flags[i]) {
    int pos = atomicAdd(cnt, 1);
    list[pos] = i;
    slot[i] = pos;
  }
}

// ---------------- pack adj rows of unique slots into bitmasks ----------------

__global__ __launch_bounds__(256) void pack_kernel(const int* __restrict__ adj,
                                                   const int* __restrict__ list,
                                                   const int* __restrict__ cntp,
                                                   unsigned* __restrict__ pk) {
  const int s = blockIdx.x >> 2;
  const int kc = (blockIdx.x & 3) * 2048;
  if (s >= *cntp) return;                    // uniform per block
  const int w = threadIdx.x >> 6, l = threadIdx.x & 63;
  const int* base = adj + (size_t)list[s] * NN + kc + w * 512;
  unsigned long long* dst = (unsigned long long*)(pk + s * 256 + (kc >> 5) + w * 16);
#pragma unroll
  for (int i = 0; i < 8; ++i) {
    unsigned long long b = __ballot(base[i * 64 + l] > 0);  // bit l = key ...+i*64+l
    if (l == 0) dst[i] = b;
  }
}

// ---------------- Wh = embedding @ W, emitted as fp16 hi/lo split ----------------

__global__ __launch_bounds__(256) void wh_kernel(const float* __restrict__ emb,
                                                 const float* __restrict__ W,
                                                 ushortT* __restrict__ Whh,
                                                 ushortT* __restrict__ Whl) {
  __shared__ float Es[32 * 65];
  __shared__ float Ws[64 * 128];
  const int t = threadIdx.x;
  const int r0 = blockIdx.x * 32;
  const int rg = t >> 5;
  const int cg = t & 31;
  float4 acc[4] = {{0,0,0,0},{0,0,0,0},{0,0,0,0},{0,0,0,0}};
  for (int kc = 0; kc < DD; kc += 64) {
    __syncthreads();
    for (int i = 0; i < 8; ++i) {
      int idx = t + 256 * i;
      int r = idx >> 6, k = idx & 63;
      Es[r * 65 + k] = emb[(r0 + r) * DD + kc + k];
    }
    for (int i = 0; i < 8; ++i) {
      int idx = t + 256 * i;
      int kr = idx >> 5, c4 = (idx & 31) * 4;
      *(float4*)&Ws[kr * 128 + c4] = *(const float4*)&W[(kc + kr) * 128 + c4];
    }
    __syncthreads();
    for (int k = 0; k < 64; ++k) {
      float4 b = *(const float4*)&Ws[k * 128 + cg * 4];
#pragma unroll
      for (int i = 0; i < 4; ++i) {
        float a = Es[(rg * 4 + i) * 65 + k];
        acc[i].x += a * b.x; acc[i].y += a * b.y;
        acc[i].z += a * b.z; acc[i].w += a * b.w;
      }
    }
  }
#pragma unroll
  for (int i = 0; i < 4; ++i) {
    int row = r0 + rg * 4 + i;
    float v[4] = {acc[i].x, acc[i].y, acc[i].z, acc[i].w};
    ushort4 hh, ll;
    ushortT* hp = (ushortT*)&hh;
    ushortT* lp = (ushortT*)&ll;
#pragma unroll
    for (int k = 0; k < 4; ++k) {
      ushortT h = f2h_bits(v[k]);
      hp[k] = h;
      lp[k] = f2h_bits(v[k] - h_bits2f(h));
    }
    *(ushort4*)&Whh[row * FF + cg * 4] = hh;
    *(ushort4*)&Whl[row * FF + cg * 4] = ll;
  }
}

// ---------------- WhT = Whh^T (128 x 8192), 64x64 tiles (bit-agnostic) ----------------

__global__ __launch_bounds__(256) void transpose_kernel(const ushortT* __restrict__ A,
                                                        ushortT* __restrict__ At) {
  __shared__ ushortT tile[64 * 72];
  const int t = threadIdx.x;
  const int r0 = (blockIdx.x >> 1) * 64, c0 = (blockIdx.x & 1) * 64;
#pragma unroll
  for (int i = 0; i < 2; ++i) {
    int idx = t + 256 * i;
    int r = idx >> 3, cb = idx & 7;
    *(ushort4*)&tile[r * 72 + ((cb ^ ((r >> 3) & 7)) * 8)] =
        *(const ushort4*)&A[(size_t)(r0 + r) * FF + c0 + cb * 8];
    *(ushort4*)&tile[r * 72 + ((cb ^ ((r >> 3) & 7)) * 8) + 4] =
        *(const ushort4*)&A[(size_t)(r0 + r) * FF + c0 + cb * 8 + 4];
  }
  __syncthreads();
#pragma unroll
  for (int i = 0; i < 2; ++i) {
    int idx = t + 256 * i;
    int f = idx >> 3, r8 = idx & 7;
    ushortT v[8];
#pragma unroll
    for (int u = 0; u < 8; ++u) {
      int row = r8 * 8 + u;
      v[u] = tile[row * 72 + (((f >> 3) ^ ((row >> 3) & 7)) * 8) + (f & 7)];
    }
    *(ushort4*)&At[(size_t)(c0 + f) * NN + r0 + r8 * 8] = *(ushort4*)&v[0];
    *(ushort4*)&At[(size_t)(c0 + f) * NN + r0 + r8 * 8 + 4] = *(ushort4*)&v[4];
  }
}

// ---------------- MFMA flash attention: fp16 2-term, 3 blocks/CU, NSPLIT 16 ----------------
// Block = 4 waves, 64 q-rows, one 512-key chunk (8 iters). S = Qhi.K + Qlo.K with
// K = fp16(Wh) single LDS copy (dbuf 2x16 KB); Q exact as fp16 hi+lo registers.
// Per iter: issue mask + next-tile global loads BEFORE the barrier (its mandatory
// vmcnt(0) drain completes them), ds_write next tile after, then compute.
// Layouts: A[m=lane&15][k=quad*8+j]; B[k=quad*8+j][n=lane&15]; C/D row=quad*4+reg, col=lane&15.

__global__ __launch_bounds__(256, 3) void attn_kernel(
    const ushortT* __restrict__ Whh, const ushortT* __restrict__ Whl,
    const ushortT* __restrict__ WhT, const unsigned* __restrict__ pk,
    const int* __restrict__ list, const int* __restrict__ cntp,
    float* __restrict__ Opart, float* __restrict__ mpart, float* __restrict__ lpart) {
  __shared__ short Kh[2][64 * 128];     // fp16 bits, chunk-XOR swizzled
  __shared__ short Ps[4][16 * 72];
  __shared__ int nid[64];

  const int cnt = *cntp;
  const int qblk = blockIdx.x >> 4, chunk = blockIdx.x & 15;
  const int q0 = qblk * 64;
  if (q0 >= cnt) return;                 // uniform: whole block exits

  const int t = threadIdx.x;
  if (t < 64) nid[t] = list[min(q0 + t, cnt - 1)];  // tail rows dup cnt-1 (junk slots unused)
  const int kt0 = chunk * KCHUNK;

  // prologue: load tile 0 (completes at the barrier)
  f16x8 sg[4];
#pragma unroll
  for (int i = 0; i < 4; ++i) {
    int idx = t + 256 * i;
    sg[i] = *(const f16x8*)(Whh + (size_t)(kt0 + (idx >> 4)) * FF + (idx & 15) * 8);
  }
  __syncthreads();                       // nid visible; sg complete
#pragma unroll
  for (int i = 0; i < 4; ++i) {
    int idx = t + 256 * i;
    int r = idx >> 4, cb = idx & 15;
    *(f16x8*)&Kh[0][r * 128 + ((cb ^ (r & 7)) * 8)] = sg[i];
  }

  const int w = t >> 6, l = t & 63, quad = l >> 4, c = l & 15;

  // Q fragments in registers for the whole K loop (A-operand: row = c); Q = qh + ql exactly
  const size_t qr = (size_t)nid[w * 16 + c] * FF;
  f16x8 qh[4], ql[4];
#pragma unroll
  for (int ks = 0; ks < 4; ++ks) {
    qh[ks] = *(const f16x8*)(Whh + qr + ks * 32 + quad * 8);
    ql[ks] = *(const f16x8*)(Whl + qr + ks * 32 + quad * 8);
  }
  int prow[4];
#pragma unroll
  for (int r = 0; r < 4; ++r) prow[r] = min(q0 + w * 16 + quad * 4 + r, cnt - 1);

  float m[4], lr[4];
#pragma unroll
  for (int r = 0; r < 4; ++r) { m[r] = -1e30f; lr[r] = 0.f; }
  f32x4 O[8] = {{0,0,0,0},{0,0,0,0},{0,0,0,0},{0,0,0,0},
                {0,0,0,0},{0,0,0,0},{0,0,0,0},{0,0,0,0}};

  for (int it = 0; it < NITER; ++it) {
    const int kt = kt0 + it * 64;
    const int cur = it & 1;
    // ---- pre-barrier issue: masks (this iter) + next K-tile loads ----
    unsigned mw0[4], mw1[4];
#pragma unroll
    for (int r = 0; r < 4; ++r) {
      uint2 mm = *(const uint2*)(pk + (size_t)prow[r] * 256 + (kt >> 5));
      mw0[r] = mm.x; mw1[r] = mm.y;
    }
    if (it + 1 < NITER) {
#pragma unroll
      for (int i = 0; i < 4; ++i) {
        int idx = t + 256 * i;
        sg[i] = *(const f16x8*)(Whh + (size_t)(kt + 64 + (idx >> 4)) * FF + (idx & 15) * 8);
      }
    }
    __syncthreads();                     // drains loads; prev reads done; Kh[cur] visible
    if (it + 1 < NITER) {
#pragma unroll
      for (int i = 0; i < 4; ++i) {
        int idx = t + 256 * i;
        int r = idx >> 4, cb = idx & 15;
        *(f16x8*)&Kh[1 - cur][r * 128 + ((cb ^ (r & 7)) * 8)] = sg[i];
      }
    }

    // ---- S = Q.K^T over 4 key-16 tiles, 2-term, K from LDS ----
    f32x4 sacc[4];
#pragma unroll
    for (int nt = 0; nt < 4; ++nt) {
      const int rb = (nt * 16 + c) * 128;
      f32x4 a = {0, 0, 0, 0};
#pragma unroll
      for (int ks = 0; ks < 4; ++ks) {
        const int off = rb + (((ks * 4 + quad) ^ (c & 7)) * 8);
        f16x8 kv = *(const f16x8*)&Kh[cur][off];
        a = __builtin_amdgcn_mfma_f32_16x16x32_f16(qh[ks], kv, a, 0, 0, 0);
        a = __builtin_amdgcn_mfma_f32_16x16x32_f16(ql[ks], kv, a, 0, 0, 0);
      }
      sacc[nt] = a;
    }

    // ---- in-wave masked online softmax ----
    float rmax[4];
#pragma unroll
    for (int r = 0; r < 4; ++r) {
      float v = -1e30f;
#pragma unroll
      for (int nt = 0; nt < 4; ++nt) {
        unsigned bit = ((nt < 2 ? mw0[r] : mw1[r]) >> ((nt & 1) * 16 + c)) & 1u;
        v = fmaxf(v, bit ? sacc[nt][r] : -1e30f);
      }
      rmax[r] = v;
    }
#pragma unroll
    for (int mk = 1; mk <= 8; mk <<= 1)
#pragma unroll
      for (int r = 0; r < 4; ++r) rmax[r] = fmaxf(rmax[r], __shfl_xor(rmax[r], mk, 16));
    float sc[4], psum[4];
#pragma unroll
    for (int r = 0; r < 4; ++r) {
      float nm = fmaxf(m[r], rmax[r]);
      sc[r] = __expf(m[r] - nm);
      m[r] = nm;
      psum[r] = 0.f;
    }
#pragma unroll
    for (int nt = 0; nt < 4; ++nt)
#pragma unroll
      for (int r = 0; r < 4; ++r) {
        unsigned bit = ((nt < 2 ? mw0[r] : mw1[r]) >> ((nt & 1) * 16 + c)) & 1u;
        float p = bit ? __expf(sacc[nt][r] - m[r]) : 0.f;
        ushortT pb = f2h_bits(p);
        Ps[w][(quad * 4 + r) * 72 + nt * 16 + c] = (short)pb;
        psum[r] += h_bits2f(pb);         // sum the rounded p for consistency
      }
#pragma unroll
    for (int mk = 1; mk <= 8; mk <<= 1)
#pragma unroll
      for (int r = 0; r < 4; ++r) psum[r] += __shfl_xor(psum[r], mk, 16);
#pragma unroll
    for (int r = 0; r < 4; ++r) lr[r] = lr[r] * sc[r] + psum[r];

    // ---- O rescale + PV (A from per-wave Ps, B from WhT global fp16) ----
#pragma unroll
    for (int ft = 0; ft < 8; ++ft)
#pragma unroll
      for (int r = 0; r < 4; ++r) O[ft][r] *= sc[r];
    f16x8 pa[2];
#pragma unroll
    for (int ks2 = 0; ks2 < 2; ++ks2)
      pa[ks2] = *(const f16x8*)&Ps[w][c * 72 + ks2 * 32 + quad * 8];
#pragma unroll
    for (int ft = 0; ft < 8; ++ft) {
      const ushortT* vp = WhT + (size_t)(ft * 16 + c) * NN + kt + quad * 8;
#pragma unroll
      for (int ks2 = 0; ks2 < 2; ++ks2) {
        f16x8 vb = *(const f16x8*)(vp + ks2 * 32);
        O[ft] = __builtin_amdgcn_mfma_f32_16x16x32_f16(pa[ks2], vb, O[ft], 0, 0, 0);
      }
    }
  }

  // ---- epilogue ----
  float* Op = Opart + (size_t)chunk * 4096 * FF;
#pragma unroll
  for (int ft = 0; ft < 8; ++ft)
#pragma unroll
    for (int r = 0; r < 4; ++r)
      Op[(size_t)(q0 + w * 16 + quad * 4 + r) * FF + ft * 16 + c] = O[ft][r];
  if (c == 0) {
#pragma unroll
    for (int r = 0; r < 4; ++r) {
      mpart[chunk * 4096 + q0 + w * 16 + quad * 4 + r] = m[r];
      lpart[chunk * 4096 + q0 + w * 16 + quad * 4 + r] = lr[r];
    }
  }
}

// ---------------- merge split-K partials, normalize, elu ----------------

__global__ __launch_bounds__(128) void combine_kernel(
    const float* __restrict__ Opart, const float* __restrict__ mpart,
    const float* __restrict__ lpart, float* __restrict__ h) {
  const int r = blockIdx.x;
  const int t = threadIdx.x;
  float mstar = -1e30f;
#pragma unroll
  for (int c = 0; c < NSPLIT; ++c) mstar = fmaxf(mstar, mpart[c * 4096 + r]);
  float lstar = 0.f, acc = 0.f;
#pragma unroll
  for (int c = 0; c < NSPLIT; ++c) {
    float wgt = __expf(mpart[c * 4096 + r] - mstar);
    lstar += wgt * lpart[c * 4096 + r];
    acc += wgt * Opart[((size_t)c * 4096 + r) * FF + t];
  }
  float v = acc / fmaxf(lstar, 1e-30f);
  h[r * FF + t] = v > 0.f ? v : expm1f(v);
}

// ---------------- gather by x, L2-normalize ----------------

__global__ __launch_bounds__(128) void out_kernel(const int* __restrict__ x,
                                                  const int* __restrict__ slot,
                                                  const float* __restrict__ h,
                                                  float* __restrict__ out) {
  const int b = blockIdx.x, t = threadIdx.x;
  const int s = slot[x[b]];
  float v = h[s * FF + t];
  float ss = v * v;
#pragma unroll
  for (int wd = 1; wd <= 32; wd <<= 1) ss += __shfl_xor(ss, wd);
  __shared__ float red[2];
  if ((t & 63) == 0) red[t >> 6] = ss;
  __syncthreads();
  float tot = red[0] + red[1];
  float scale = 1.f / fmaxf(sqrtf(tot), 1e-12f);
  out[b * FF + t] = v * scale;
}

// ---------------- launch ----------------

extern "C" void kernel_launch(void* const* d_in, const int* in_sizes, int n_in,
                              void* d_out, int out_size, void* d_ws, size_t ws_size,
                              hipStream_t stream) {
  const int*   x   = (const int*)d_in[0];
  const int*   adj = (const int*)d_in[1];
  const float* emb = (const float*)d_in[2];
  const float* W   = (const float*)d_in[3];
  float* out = (float*)d_out;

  char* base = (char*)d_ws;                              // ~44.6 MB total
  ushortT* Whh = (ushortT*)(base);                       //  0 .. 2 MB  (fp16 hi)
  ushortT* Whl = (ushortT*)(base + 2097152);             //  2 .. 4 MB  (fp16 lo; dead after attn)
  float*   h   = (float*)(base + 2097152);               //  aliases Whl
  ushortT* WhT = (ushortT*)(base + 4194304);             //  4 .. 6 MB
  float* Opart = (float*)(base + 6291456);               //  6 .. 39.8 MB (16 chunks)
  float* mpart = (float*)(base + 39845888);
  float* lpart = (float*)(base + 40108032);
  unsigned* pk = (unsigned*)(base + 40370176);           //  4 MB packed adj bits
  int*   flags = (int*)(base + 44564480);
  int*   list  = (int*)(base + 44597248);
  int*   slot  = (int*)(base + 44613632);
  int*   cnt   = (int*)(base + 44646400);
  (void)in_sizes; (void)n_in; (void)out_size; (void)ws_size;

  hipLaunchKernelGGL(init_kernel,      dim3(NN / 256), dim3(256), 0, stream, flags, cnt);
  hipLaunchKernelGGL(scatter_kernel,   dim3(BB / 256), dim3(256), 0, stream, x, flags);
  hipLaunchKernelGGL(compact_kernel,   dim3(NN / 256), dim3(256), 0, stream, flags, cnt, list, slot);
  hipLaunchKernelGGL(pack_kernel,      dim3(4096 * 4), dim3(256), 0, stream, adj, list, cnt, pk);
  hipLaunchKernelGGL(wh_kernel,        dim3(NN / 32),  dim3(256), 0, stream, emb, W, Whh, Whl);
  hipLaunchKernelGGL(transpose_kernel, dim3((NN / 64) * 2), dim3(256), 0, stream, Whh, WhT);
  hipLaunchKernelGGL(attn_kernel,      dim3((BB / 64) * NSPLIT), dim3(256), 0, stream,
                     Whh, Whl, WhT, pk, list, cnt, Opart, mpart, lpart);
  hipLaunchKernelGGL(combine_kernel,   dim3(4096), dim3(128), 0, stream, Opart, mpart, lpart, h);
  hipLaunchKernelGGL(out_kernel,       dim3(BB),   dim3(128), 0, stream, x, slot, h, out);
}

// Round 8
// 468.311 us; speedup vs baseline: 1.0150x; 1.0150x over previous
//
#include <hip/hip_runtime.h>

#define NN 8192
#define DD 256
#define FF 128
#define BB 4096
#define NSPLIT 16
#define KCHUNK (NN / NSPLIT)   // 512 keys per split-K chunk
#define NITER (KCHUNK / 64)    // 8 key-tiles per chunk

typedef unsigned short ushortT;
typedef _Float16 f16;
typedef __attribute__((ext_vector_type(8))) _Float16 f16x8;
typedef __attribute__((ext_vector_type(4))) float f32x4;

__device__ __forceinline__ ushortT f2h_bits(float f) {
  f16 h = (f16)f; ushortT u; __builtin_memcpy(&u, &h, 2); return u;
}
__device__ __forceinline__ float h_bits2f(ushortT u) {
  f16 h; __builtin_memcpy(&h, &u, 2); return (float)h;
}

// ---------------- single-block unique(x) dedup (replaces init+scatter+compact) ----------------

__global__ __launch_bounds__(1024) void dedup_kernel(const int* __restrict__ x,
                                                     int* __restrict__ list,
                                                     int* __restrict__ slot,
                                                     int* __restrict__ cnt) {
  __shared__ int flags[NN];     // 32 KB
  __shared__ int lcnt;
  const int t = threadIdx.x;
  for (int i = t; i < NN; i += 1024) flags[i] = 0;
  if (t == 0) lcnt = 0;
  __syncthreads();
  for (int i = t; i < BB; i += 1024) flags[x[i]] = 1;   // benign race: all write 1
  __syncthreads();
  for (int i = t; i < NN; i += 1024)
    if (flags[i]) {
      int pos = atomicAdd(&lcnt, 1);    // order irrelevant: h addressed via slot[]
      list[pos] = i;
      slot[i] = pos;
    }
  __syncthreads();
  if (t == 0) *cnt = lcnt;
}

// ---------------- pack adj rows of unique slots into bitmasks ----------------

__global__ __launch_bounds__(256) void pack_kernel(const int* __restrict__ adj,
                                                   const int* __restrict__ list,
                                                   const int* __restrict__ cntp,
                                                   unsigned* __restrict__ pk) {
  const int s = blockIdx.x >> 2;
  const int kc = (blockIdx.x & 3) * 2048;
  if (s >= *cntp) return;                    // uniform per block
  const int w = threadIdx.x >> 6, l = threadIdx.x & 63;
  const int* base = adj + (size_t)list[s] * NN + kc + w * 512;
  unsigned long long* dst = (unsigned long long*)(pk + s * 256 + (kc >> 5) + w * 16);
#pragma unroll
  for (int i = 0; i < 8; ++i) {
    unsigned long long b = __ballot(base[i * 64 + l] > 0);  // bit l = key ...+i*64+l
    if (l == 0) dst[i] = b;
  }
}

// ---------------- Wh = embedding @ W -> fp16 hi/lo + direct WhT emission ----------------

__global__ __launch_bounds__(256) void wh_kernel(const float* __restrict__ emb,
                                                 const float* __restrict__ W,
                                                 ushortT* __restrict__ Whh,
                                                 ushortT* __restrict__ Whl,
                                                 ushortT* __restrict__ WhT) {
  __shared__ float Es[32 * 65];
  __shared__ float Ws[64 * 128];
  const int t = threadIdx.x;
  const int r0 = blockIdx.x * 32;
  const int rg = t >> 5;
  const int cg = t & 31;
  float4 acc[4] = {{0,0,0,0},{0,0,0,0},{0,0,0,0},{0,0,0,0}};
  for (int kc = 0; kc < DD; kc += 64) {
    __syncthreads();
    for (int i = 0; i < 8; ++i) {
      int idx = t + 256 * i;
      int r = idx >> 6, k = idx & 63;
      Es[r * 65 + k] = emb[(r0 + r) * DD + kc + k];
    }
    for (int i = 0; i < 8; ++i) {
      int idx = t + 256 * i;
      int kr = idx >> 5, c4 = (idx & 31) * 4;
      *(float4*)&Ws[kr * 128 + c4] = *(const float4*)&W[(kc + kr) * 128 + c4];
    }
    __syncthreads();
    for (int k = 0; k < 64; ++k) {
      float4 b = *(const float4*)&Ws[k * 128 + cg * 4];
#pragma unroll
      for (int i = 0; i < 4; ++i) {
        float a = Es[(rg * 4 + i) * 65 + k];
        acc[i].x += a * b.x; acc[i].y += a * b.y;
        acc[i].z += a * b.z; acc[i].w += a * b.w;
      }
    }
  }
  ushortT hv[4][4];
#pragma unroll
  for (int i = 0; i < 4; ++i) {
    int row = r0 + rg * 4 + i;
    float v[4] = {acc[i].x, acc[i].y, acc[i].z, acc[i].w};
    ushort4 hh, ll;
    ushortT* hp = (ushortT*)&hh;
    ushortT* lp = (ushortT*)&ll;
#pragma unroll
    for (int k = 0; k < 4; ++k) {
      ushortT h = f2h_bits(v[k]);
      hp[k] = h;
      lp[k] = f2h_bits(v[k] - h_bits2f(h));
      hv[k][i] = h;                      // [col][row] for transposed store
    }
    *(ushort4*)&Whh[row * FF + cg * 4] = hh;
    *(ushort4*)&Whl[row * FF + cg * 4] = ll;
  }
#pragma unroll
  for (int k = 0; k < 4; ++k)            // WhT[col][r0+rg*4 .. +3]
    *(ushort4*)&WhT[(size_t)(cg * 4 + k) * NN + r0 + rg * 4] = *(ushort4*)&hv[k][0];
}

// ---------------- MFMA flash attention: fp16 2-term Q, exp2 domain ----------------
// Block = 4 waves, 64 q-rows, one 512-key chunk (8 iters). S' = log2e*Q.K via
// log2e folded into the Q hi/lo split; softmax in exp2 domain (native v_exp_f32).
// K = fp16(Wh) single LDS copy, dbuf 2x16 KB, 1 barrier/iter (next tile's loads
// issued pre-barrier, drained by its vmcnt(0), ds_written post-barrier).
// Layouts: A[m=lane&15][k=quad*8+j]; B[k=quad*8+j][n=lane&15]; C/D row=quad*4+reg, col=lane&15.

__global__ __launch_bounds__(256, 3) void attn_kernel(
    const ushortT* __restrict__ Whh, const ushortT* __restrict__ Whl,
    const ushortT* __restrict__ WhT, const unsigned* __restrict__ pk,
    const int* __restrict__ list, const int* __restrict__ cntp,
    float* __restrict__ Opart, float* __restrict__ mpart, float* __restrict__ lpart) {
  __shared__ short Kh[2][64 * 128];     // fp16 bits, chunk-XOR swizzled
  __shared__ short Ps[4][16 * 72];
  __shared__ int nid[64];

  const int cnt = *cntp;
  const int qblk = blockIdx.x >> 4, chunk = blockIdx.x & 15;
  const int q0 = qblk * 64;
  if (q0 >= cnt) return;                 // uniform: whole block exits

  const int t = threadIdx.x;
  if (t < 64) nid[t] = list[min(q0 + t, cnt - 1)];  // tail rows dup cnt-1 (junk slots unused)
  const int kt0 = chunk * KCHUNK;

  // prologue: load tile 0 (completes at the barrier)
  f16x8 sg[4];
#pragma unroll
  for (int i = 0; i < 4; ++i) {
    int idx = t + 256 * i;
    sg[i] = *(const f16x8*)(Whh + (size_t)(kt0 + (idx >> 4)) * FF + (idx & 15) * 8);
  }
  __syncthreads();                       // nid visible; sg complete
#pragma unroll
  for (int i = 0; i < 4; ++i) {
    int idx = t + 256 * i;
    int r = idx >> 4, cb = idx & 15;
    *(f16x8*)&Kh[0][r * 128 + ((cb ^ (r & 7)) * 8)] = sg[i];
  }

  const int w = t >> 6, l = t & 63, quad = l >> 4, c = l & 15;

  // Q fragments scaled by log2(e), re-split hi/lo (exact residual), regs for whole loop
  const size_t qr = (size_t)nid[w * 16 + c] * FF;
  f16x8 qh[4], ql[4];
#pragma unroll
  for (int ks = 0; ks < 4; ++ks) {
    f16x8 h8 = *(const f16x8*)(Whh + qr + ks * 32 + quad * 8);
    f16x8 l8 = *(const f16x8*)(Whl + qr + ks * 32 + quad * 8);
#pragma unroll
    for (int u = 0; u < 8; ++u) {
      float q = ((float)h8[u] + (float)l8[u]) * 1.4426950408889634f;
      f16 hi = (f16)q;
      qh[ks][u] = hi;
      ql[ks][u] = (f16)(q - (float)hi);
    }
  }
  int prow[4];
#pragma unroll
  for (int r = 0; r < 4; ++r) prow[r] = min(q0 + w * 16 + quad * 4 + r, cnt - 1);

  float m[4], lr[4];
#pragma unroll
  for (int r = 0; r < 4; ++r) { m[r] = -1e30f; lr[r] = 0.f; }
  f32x4 O[8] = {{0,0,0,0},{0,0,0,0},{0,0,0,0},{0,0,0,0},
                {0,0,0,0},{0,0,0,0},{0,0,0,0},{0,0,0,0}};

  for (int it = 0; it < NITER; ++it) {
    const int kt = kt0 + it * 64;
    const int cur = it & 1;
    if (it + 1 < NITER) {                // pre-barrier issue of next tile's loads
#pragma unroll
      for (int i = 0; i < 4; ++i) {
        int idx = t + 256 * i;
        sg[i] = *(const f16x8*)(Whh + (size_t)(kt + 64 + (idx >> 4)) * FF + (idx & 15) * 8);
      }
    }
    __syncthreads();                     // drains loads; prev reads done; Kh[cur] visible
    if (it + 1 < NITER) {
#pragma unroll
      for (int i = 0; i < 4; ++i) {
        int idx = t + 256 * i;
        int r = idx >> 4, cb = idx & 15;
        *(f16x8*)&Kh[1 - cur][r * 128 + ((cb ^ (r & 7)) * 8)] = sg[i];
      }
    }
    // ---- masks (L2 broadcast loads, consumed post-S) ----
    unsigned mw0[4], mw1[4];
#pragma unroll
    for (int r = 0; r < 4; ++r) {
      uint2 mm = *(const uint2*)(pk + (size_t)prow[r] * 256 + (kt >> 5));
      mw0[r] = mm.x; mw1[r] = mm.y;
    }

    // ---- S' = (log2e*Q).K^T over 4 key-16 tiles, 2-term, K from LDS ----
    f32x4 sacc[4];
#pragma unroll
    for (int nt = 0; nt < 4; ++nt) {
      const int rb = (nt * 16 + c) * 128;
      f32x4 a = {0, 0, 0, 0};
#pragma unroll
      for (int ks = 0; ks < 4; ++ks) {
        const int off = rb + (((ks * 4 + quad) ^ (c & 7)) * 8);
        f16x8 kv = *(const f16x8*)&Kh[cur][off];
        a = __builtin_amdgcn_mfma_f32_16x16x32_f16(qh[ks], kv, a, 0, 0, 0);
        a = __builtin_amdgcn_mfma_f32_16x16x32_f16(ql[ks], kv, a, 0, 0, 0);
      }
      sacc[nt] = a;
    }

    // ---- in-wave masked online softmax (exp2 domain) ----
    float rmax[4];
#pragma unroll
    for (int r = 0; r < 4; ++r) {
      float v = -1e30f;
#pragma unroll
      for (int nt = 0; nt < 4; ++nt) {
        unsigned bit = ((nt < 2 ? mw0[r] : mw1[r]) >> ((nt & 1) * 16 + c)) & 1u;
        v = fmaxf(v, bit ? sacc[nt][r] : -1e30f);
      }
      rmax[r] = v;
    }
#pragma unroll
    for (int mk = 1; mk <= 8; mk <<= 1)
#pragma unroll
      for (int r = 0; r < 4; ++r) rmax[r] = fmaxf(rmax[r], __shfl_xor(rmax[r], mk, 16));
    float sc[4], psum[4];
#pragma unroll
    for (int r = 0; r < 4; ++r) {
      float nm = fmaxf(m[r], rmax[r]);
      sc[r] = exp2f(m[r] - nm);
      m[r] = nm;
      psum[r] = 0.f;
    }
#pragma unroll
    for (int nt = 0; nt < 4; ++nt)
#pragma unroll
      for (int r = 0; r < 4; ++r) {
        unsigned bit = ((nt < 2 ? mw0[r] : mw1[r]) >> ((nt & 1) * 16 + c)) & 1u;
        float p = bit ? exp2f(sacc[nt][r] - m[r]) : 0.f;
        ushortT pb = f2h_bits(p);
        Ps[w][(quad * 4 + r) * 72 + nt * 16 + c] = (short)pb;
        psum[r] += h_bits2f(pb);         // sum the rounded p for consistency
      }
#pragma unroll
    for (int mk = 1; mk <= 8; mk <<= 1)
#pragma unroll
      for (int r = 0; r < 4; ++r) psum[r] += __shfl_xor(psum[r], mk, 16);
#pragma unroll
    for (int r = 0; r < 4; ++r) lr[r] = lr[r] * sc[r] + psum[r];

    // ---- O rescale + PV (A from per-wave Ps, B from WhT global fp16) ----
#pragma unroll
    for (int ft = 0; ft < 8; ++ft)
#pragma unroll
      for (int r = 0; r < 4; ++r) O[ft][r] *= sc[r];
    f16x8 pa[2];
#pragma unroll
    for (int ks2 = 0; ks2 < 2; ++ks2)
      pa[ks2] = *(const f16x8*)&Ps[w][c * 72 + ks2 * 32 + quad * 8];
#pragma unroll
    for (int ft = 0; ft < 8; ++ft) {
      const ushortT* vp = WhT + (size_t)(ft * 16 + c) * NN + kt + quad * 8;
#pragma unroll
      for (int ks2 = 0; ks2 < 2; ++ks2) {
        f16x8 vb = *(const f16x8*)(vp + ks2 * 32);
        O[ft] = __builtin_amdgcn_mfma_f32_16x16x32_f16(pa[ks2], vb, O[ft], 0, 0, 0);
      }
    }
  }

  // ---- epilogue ----
  float* Op = Opart + (size_t)chunk * 4096 * FF;
#pragma unroll
  for (int ft = 0; ft < 8; ++ft)
#pragma unroll
    for (int r = 0; r < 4; ++r)
      Op[(size_t)(q0 + w * 16 + quad * 4 + r) * FF + ft * 16 + c] = O[ft][r];
  if (c == 0) {
#pragma unroll
    for (int r = 0; r < 4; ++r) {
      mpart[chunk * 4096 + q0 + w * 16 + quad * 4 + r] = m[r];
      lpart[chunk * 4096 + q0 + w * 16 + quad * 4 + r] = lr[r];
    }
  }
}

// ---------------- fused: merge split-K partials, elu, gather, L2-normalize ----------------

__global__ __launch_bounds__(128) void combine_out(
    const int* __restrict__ x, const int* __restrict__ slot,
    const float* __restrict__ Opart, const float* __restrict__ mpart,
    const float* __restrict__ lpart, float* __restrict__ out) {
  const int b = blockIdx.x, t = threadIdx.x;
  const int s = slot[x[b]];
  float mstar = -1e30f;
#pragma unroll
  for (int c = 0; c < NSPLIT; ++c) mstar = fmaxf(mstar, mpart[c * 4096 + s]);
  float lstar = 0.f, acc = 0.f;
#pragma unroll
  for (int c = 0; c < NSPLIT; ++c) {
    float wgt = exp2f(mpart[c * 4096 + s] - mstar);
    lstar += wgt * lpart[c * 4096 + s];
    acc += wgt * Opart[((size_t)c * 4096 + s) * FF + t];
  }
  float v = acc / fmaxf(lstar, 1e-30f);
  v = v > 0.f ? v : expm1f(v);           // elu
  float ss = v * v;
#pragma unroll
  for (int wd = 1; wd <= 32; wd <<= 1) ss += __shfl_xor(ss, wd);  // 64-lane wave sum
  __shared__ float red[2];
  if ((t & 63) == 0) red[t >> 6] = ss;
  __syncthreads();
  float tot = red[0] + red[1];
  float scale = 1.f / fmaxf(sqrtf(tot), 1e-12f);
  out[b * FF + t] = v * scale;
}

// ---------------- launch ----------------

extern "C" void kernel_launch(void* const* d_in, const int* in_sizes, int n_in,
                              void* d_out, int out_size, void* d_ws, size_t ws_size,
                              hipStream_t stream) {
  const int*   x   = (const int*)d_in[0];
  const int*   adj = (const int*)d_in[1];
  const float* emb = (const float*)d_in[2];
  const float* W   = (const float*)d_in[3];
  float* out = (float*)d_out;

  char* base = (char*)d_ws;                              // ~44.6 MB total
  ushortT* Whh = (ushortT*)(base);                       //  0 .. 2 MB  (fp16 hi)
  ushortT* Whl = (ushortT*)(base + 2097152);             //  2 .. 4 MB  (fp16 lo)
  ushortT* WhT = (ushortT*)(base + 4194304);             //  4 .. 6 MB
  float* Opart = (float*)(base + 6291456);               //  6 .. 39.8 MB (16 chunks)
  float* mpart = (float*)(base + 39845888);
  float* lpart = (float*)(base + 40108032);
  unsigned* pk = (unsigned*)(base + 40370176);           //  4 MB packed adj bits
  int*   list  = (int*)(base + 44564480);
  int*   slot  = (int*)(base + 44580864);
  int*   cnt   = (int*)(base + 44613632);
  (void)in_sizes; (void)n_in; (void)out_size; (void)ws_size;

  hipLaunchKernelGGL(dedup_kernel, dim3(1),        dim3(1024), 0, stream, x, list, slot, cnt);
  hipLaunchKernelGGL(pack_kernel,  dim3(4096 * 4), dim3(256),  0, stream, adj, list, cnt, pk);
  hipLaunchKernelGGL(wh_kernel,    dim3(NN / 32),  dim3(256),  0, stream, emb, W, Whh, Whl, WhT);
  hipLaunchKernelGGL(attn_kernel,  dim3((BB / 64) * NSPLIT), dim3(256), 0, stream,
                     Whh, Whl, WhT, pk, list, cnt, Opart, mpart, lpart);
  hipLaunchKernelGGL(combine_out,  dim3(BB), dim3(128), 0, stream,
                     x, slot, Opart, mpart, lpart, out);
}